// Round 5
// baseline (113.954 us; speedup 1.0000x reference)
//
#include <hip/hip_runtime.h>
#include <hip/hip_bf16.h>

#define BN 512   // batch
#define DD 512   // feature dim
#define LL 24    // label dim
#define NB 512   // one block per row
#define NT 256   // 4 waves per block

typedef __attribute__((ext_vector_type(8))) short short8;  // 8 bf16 = 4 VGPR
typedef __attribute__((ext_vector_type(4))) float f32x4;

// ws layout (float words): [0, 1024) per-block slots: block b -> {sum(f32), cnt(u32)}
// Slots written unconditionally by every block (poison-safe, no init, no atomics).

__device__ __forceinline__ unsigned pk_bf16(float lo, float hi) {
    __hip_bfloat162 p = __float22bfloat162_rn(make_float2(lo, hi));
    unsigned u;
    __builtin_memcpy(&u, &p, 4);     // type-pun; bit_cast rejects non-trivial ctor
    return u;
}

// pack 8 f32 -> bf16 fragment via v_cvt_pk_bf16_f32, accumulate sum of squares
// (identical rounding path to the verified R0 kernel -> identical numerics)
__device__ __forceinline__ short8 pack8_pk(float4 x, float4 y, float& nrm) {
    nrm = fmaf(x.x, x.x, nrm); nrm = fmaf(x.y, x.y, nrm);
    nrm = fmaf(x.z, x.z, nrm); nrm = fmaf(x.w, x.w, nrm);
    nrm = fmaf(y.x, y.x, nrm); nrm = fmaf(y.y, y.y, nrm);
    nrm = fmaf(y.z, y.z, nrm); nrm = fmaf(y.w, y.w, nrm);
    union { uint4 u; short8 s; } cv;
    cv.u.x = pk_bf16(x.x, x.y);
    cv.u.y = pk_bf16(x.z, x.w);
    cv.u.z = pk_bf16(y.x, y.y);
    cv.u.w = pk_bf16(y.z, y.w);
    return cv.s;
}

// ---------------- main kernel: one row per block, MFMA matvec distances ------
// Phase A: all 512 label masks (each thread: rows t, t+256); wave-redundant
//          n_i; wave 0 packs s_i to bf16 in LDS (1 KB).
// Phase B: block-uniform activity check; ~60% of blocks exit (P(neg pair)
//          = (3/4)^24 ~ 0.001), writing zero slots.
// Phase C: distance row via MFMA matvec G_i = S . s_i. A-operand = s_i in all
//          16 fragment rows (lane (q,r) needs s_i[k0+8q .. +8) -- uniform per
//          q-group, broadcast ds_read of the packed copy). B-fragment loads +
//          bf16 pack exactly as R0 (verified absmax=0). C-layout (verified):
//          col = lane&15, row = q*4+p; all rows identical -> acc[0] at q==0
//          lanes gives d2 for col jb+r.
// Phase D: wave 0 runs the R2-verified ballot triplet loop from LDS.
__global__ __launch_bounds__(NT) void row_kernel(
    const float* __restrict__ S, const int* __restrict__ labels,
    float* __restrict__ slots)
{
    __shared__ unsigned mask_lds[BN];
    __shared__ float    d_lds[BN];
    __shared__ uint4    si_bf4[64];        // s_i as 512 bf16 (lane L: k in [8L,8L+8))
    __shared__ int      anyneg_s;

    const int t    = threadIdx.x;
    const int lane = t & 63;
    const int w    = t >> 6;               // wave 0..3
    const int i    = blockIdx.x;

    if (t == 0) anyneg_s = 0;

    // ---- phase A: masks for rows t and t+256 (24 ints = 6 x int4 each) ----
#pragma unroll
    for (int rr = 0; rr < 2; rr++) {
        const int row = t + rr * NT;
        const int4* lab4 = (const int4*)(labels + (size_t)row * LL);
        unsigned m = 0;
#pragma unroll
        for (int v = 0; v < 6; v++) {
            int4 x = lab4[v];
            m |= (x.x ? 1u : 0u) << (4 * v)
               | (x.y ? 1u : 0u) << (4 * v + 1)
               | (x.z ? 1u : 0u) << (4 * v + 2)
               | (x.w ? 1u : 0u) << (4 * v + 3);
        }
        mask_lds[row] = m;
    }

    // ---- n_i (per-wave redundant, f32 exact) + wave-0 bf16 pack of s_i ----
    const float* sip = S + (size_t)i * DD + 8 * lane;
    const float4 s0 = *(const float4*)sip;
    const float4 s1 = *(const float4*)(sip + 4);
    float ni = 0.f;
    ni = fmaf(s0.x, s0.x, ni); ni = fmaf(s0.y, s0.y, ni);
    ni = fmaf(s0.z, s0.z, ni); ni = fmaf(s0.w, s0.w, ni);
    ni = fmaf(s1.x, s1.x, ni); ni = fmaf(s1.y, s1.y, ni);
    ni = fmaf(s1.z, s1.z, ni); ni = fmaf(s1.w, s1.w, ni);
#pragma unroll
    for (int off = 1; off < 64; off <<= 1) ni += __shfl_xor(ni, off);
    if (w == 0) {
        uint4 pk;
        pk.x = pk_bf16(s0.x, s0.y); pk.y = pk_bf16(s0.z, s0.w);
        pk.z = pk_bf16(s1.x, s1.y); pk.w = pk_bf16(s1.z, s1.w);
        si_bf4[lane] = pk;
    }
    __syncthreads();                       // masks + si_bf4 + flag init visible

    // ---- phase B: activity (row i has >=1 negative?) ----
    const unsigned mi = mask_lds[i];
    if (((mi & mask_lds[t]) == 0u) || ((mi & mask_lds[t + NT]) == 0u)) anyneg_s = 1;
    __syncthreads();                       // flag final (block-uniform)

    if (!anyneg_s) {                       // uniform early exit, poison-safe slots
        if (t == 0) { slots[2 * i] = 0.f; ((unsigned*)slots)[2 * i + 1] = 0u; }
        return;
    }

    // ---- phase C: distance row via MFMA matvec ----
    const int r = lane & 15;               // fragment col (j within tile)
    const int q = lane >> 4;               // k-quarter
#pragma unroll
    for (int tt = 0; tt < 8; tt++) {
        const int jb = (w + 4 * tt) * 16;  // wave w: tiles w, w+4, ..., w+28
        const float* pB = S + (size_t)(jb + r) * DD + q * 8;

        f32x4 acc = {0.f, 0.f, 0.f, 0.f};
        float nB = 0.f;
        float4 bx = *(const float4*)pB, by = *(const float4*)(pB + 4);

        for (int k0 = 0; k0 < DD; k0 += 32) {
            float4 nbx, nby;
            const int kn = k0 + 32;
            if (kn < DD) {                 // uniform depth-1 prefetch (R0 pattern)
                nbx = *(const float4*)(pB + kn);
                nby = *(const float4*)(pB + kn + 4);
            }
            union { uint4 u; short8 s; } av;
            av.u = si_bf4[(k0 >> 3) + q];  // s_i[k0+8q .. +8), broadcast per q-group
            short8 bf = pack8_pk(bx, by, nB);
            acc = __builtin_amdgcn_mfma_f32_16x16x32_bf16(av.s, bf, acc, 0, 0, 0);
            bx = nbx; by = nby;
        }
        // n_j: row jb+r covered by lanes {r, r+16, r+32, r+48} (disjoint k)
        nB += __shfl_xor(nB, 16); nB += __shfl_xor(nB, 32);
        if (q == 0) {
            const int j = jb + r;
            const float d2 = ni + nB - 2.f * acc[0];
            d_lds[j] = (j == i) ? 0.f : sqrtf(fmaxf(d2, 0.f));
        }
    }
    __syncthreads();                       // distance row complete

    // ---- phase D: triplet loop (wave 0 only; R2-verified structure) ----
    float sum = 0.f; unsigned cnt = 0u;
    if (w == 0) {
        unsigned long long pb[8]; float dv[8];
#pragma unroll
        for (int c = 0; c < 8; c++) {
            pb[c] = __ballot((mi & mask_lds[c * 64 + lane]) != 0u);
            dv[c] = d_lds[c * 64 + lane];
        }
#pragma unroll
        for (int c = 0; c < 8; c++) {
            unsigned long long nb = ~pb[c];
            while (nb) {                   // wave-uniform, ~0.5 iters/row avg
                const int k = __ffsll(nb) - 1;
                nb &= nb - 1;
                const float dk = __shfl(dv[c], k);
#pragma unroll
                for (int c2 = 0; c2 < 8; c2++) {
                    if ((pb[c2] >> lane) & 1ull) {   // lane's j is a positive
                        const float v = dv[c2] - dk;
                        sum += fmaxf(v, 0.0f);
                        cnt += (v > 1e-16f) ? 1u : 0u;
                    }
                }
            }
        }
#pragma unroll
        for (int off = 32; off > 0; off >>= 1) {
            sum += __shfl_down(sum, off);
            cnt += __shfl_down(cnt, off);
        }
    }

    if (t == 0) {                          // unconditional slot write
        slots[2 * i]                  = sum;
        ((unsigned*)slots)[2 * i + 1] = cnt;
    }
}

// ---------------- finalize: reduce 512 slots, divide (R4-verified) -----------
__global__ __launch_bounds__(256) void finalize_kernel(
    const float* __restrict__ slots, float* __restrict__ out)
{
    __shared__ float    wsum[4];
    __shared__ unsigned wcnt[4];
    const int t    = threadIdx.x;          // 256
    const int lane = t & 63;
    const int w    = t >> 6;

    float s = 0.f; unsigned c = 0u;
    for (int b = t; b < NB; b += 256) {
        s += slots[2 * b];
        c += ((const unsigned*)slots)[2 * b + 1];
    }
#pragma unroll
    for (int off = 32; off > 0; off >>= 1) {
        s += __shfl_down(s, off);
        c += __shfl_down(c, off);
    }
    if (lane == 0) { wsum[w] = s; wcnt[w] = c; }
    __syncthreads();
    if (t == 0) {
        s = wsum[0] + wsum[1] + wsum[2] + wsum[3];
        c = wcnt[0] + wcnt[1] + wcnt[2] + wcnt[3];
        out[0] = s / ((float)c + 1e-16f);
    }
}

extern "C" void kernel_launch(void* const* d_in, const int* in_sizes, int n_in,
                              void* d_out, int out_size, void* d_ws, size_t ws_size,
                              hipStream_t stream) {
    const float* src    = (const float*)d_in[0];
    const int*   labels = (const int*)d_in[1];
    float* slots = (float*)d_ws;

    hipLaunchKernelGGL(row_kernel,      dim3(NB), dim3(NT),  0, stream, src, labels, slots);
    hipLaunchKernelGGL(finalize_kernel, dim3(1),  dim3(256), 0, stream, slots, (float*)d_out);
}